// Round 2
// baseline (1712.337 us; speedup 1.0000x reference)
//
#include <hip/hip_runtime.h>
#include <hip/hip_bf16.h>
#include <stdint.h>

#define B_ 16
#define T_ 1024
#define EMBED_ 128
#define HID_ 256
#define G4_ 1024
#define NC_ 8000
#define M_ (B_*T_)

typedef short bf16x8 __attribute__((ext_vector_type(8)));
typedef float f32x4 __attribute__((ext_vector_type(4)));

#if defined(__has_builtin)
#if __has_builtin(__builtin_amdgcn_sdot4)
#define SDOT4(a,b,c) __builtin_amdgcn_sdot4((a),(b),(c),false)
#endif
#endif
#ifndef SDOT4
__device__ __forceinline__ int sdot4_sw(int a, int b, int c) {
    c += (int)(signed char)(a)       * (int)(signed char)(b);
    c += (int)(signed char)(a >> 8)  * (int)(signed char)(b >> 8);
    c += (int)(signed char)(a >> 16) * (int)(signed char)(b >> 16);
    c += (int)(signed char)(a >> 24) * (int)(signed char)(b >> 24);
    return c;
}
#define SDOT4(a,b,c) sdot4_sw((a),(b),(c))
#endif

__device__ __forceinline__ float sigmoid_f(float x) {
    float e = __expf(-x);
    return __builtin_amdgcn_rcpf(1.f + e);   // x<<0: e=inf -> 0 ; x>>0: e=0 -> 1
}

// ---------------- embed + concat -> bf16 (16384 x 256) ----------------
__global__ void embed_kernel(const int* __restrict__ x,
                             const float* __restrict__ ew,
                             const float* __restrict__ lw,
                             __hip_bfloat16* __restrict__ inp) {
    int m = blockIdx.x;          // b*T + t
    int e = threadIdx.x;         // 0..255
    int i0 = x[2 * m];
    int i1 = x[2 * m + 1];
    float v = (e < EMBED_) ? ew[i0 * EMBED_ + e] : lw[i1 * EMBED_ + (e - EMBED_)];
    inp[m * 256 + e] = __float2bfloat16(v);
}

// ---------------- f32 -> bf16 ----------------
__global__ void f2bf_kernel(const float* __restrict__ in,
                            __hip_bfloat16* __restrict__ out, int n) {
    int i = blockIdx.x * blockDim.x + threadIdx.x;
    if (i < n) out[i] = __float2bfloat16(in[i]);
}

// ---------------- per-row int8 quant of W_hh (1024 rows x 256) ----------------
__global__ void quant_whh_kernel(const float* __restrict__ whh,
                                 int* __restrict__ wq, float* __restrict__ wscale) {
    int r = blockIdx.x;      // 1024
    int lane = threadIdx.x;  // 64
    float4 v = ((const float4*)(whh + r * HID_))[lane];
    float m = fmaxf(fmaxf(fabsf(v.x), fabsf(v.y)), fmaxf(fabsf(v.z), fabsf(v.w)));
    #pragma unroll
    for (int off = 32; off; off >>= 1) m = fmaxf(m, __shfl_xor(m, off, 64));
    m = fmaxf(m, 1e-20f);
    float inv = 127.f / m;
    int q0 = __float2int_rn(v.x * inv) & 255;
    int q1 = __float2int_rn(v.y * inv) & 255;
    int q2 = __float2int_rn(v.z * inv) & 255;
    int q3 = __float2int_rn(v.w * inv) & 255;
    wq[r * 64 + lane] = q0 | (q1 << 8) | (q2 << 16) | (q3 << 24);
    if (lane == 0) wscale[r] = m * (1.f / 127.f);
}

// ---------------- bf16 MFMA GEMM: C[m,n] = sum_k A[m,k]*B[n,k] + bias ----------------
// A: M x 256 (row-major, K contig), B: N x 256 (row-major, K contig)
// out_mode 0: C[m*N+n] ; out_mode 1: C[(t*16+b)*1024+n] with m=b*1024+t
__global__ __launch_bounds__(256, 4)
void gemm_bf16_kernel(const __hip_bfloat16* __restrict__ A,
                      const __hip_bfloat16* __restrict__ Bm,
                      const float* __restrict__ bias1,
                      const float* __restrict__ bias2,
                      float* __restrict__ C,
                      int N, int out_mode) {
    __shared__ short As[64][136];   // pad: row stride 272B -> 2-way bank alias (free)
    __shared__ short Bs[64][136];
    const int tid = threadIdx.x;
    const int m0 = blockIdx.y * 64;
    const int n0 = blockIdx.x * 64;
    const int w = tid >> 6;
    const int lane = tid & 63;
    const int l15 = lane & 15;
    const int q = lane >> 4;

    f32x4 zero4 = {0.f, 0.f, 0.f, 0.f};
    f32x4 acc[4] = {zero4, zero4, zero4, zero4};

    const int r = tid >> 2;
    const int cbase = tid & 3;

    for (int ko = 0; ko < 256; ko += 128) {
        #pragma unroll
        for (int i = 0; i < 4; ++i) {
            int c = cbase + (i << 2);  // 0..15 chunks of 8 elems
            uint4 av = ((const uint4*)A)[(size_t)(m0 + r) * 32 + (ko >> 3) + c];
            *((uint4*)&As[r][c * 8]) = av;
            uint4 bv = ((const uint4*)Bm)[(size_t)(n0 + r) * 32 + (ko >> 3) + c];
            *((uint4*)&Bs[r][c * 8]) = bv;
        }
        __syncthreads();
        #pragma unroll
        for (int kc = 0; kc < 4; ++kc) {
            bf16x8 af = *((const bf16x8*)&As[w * 16 + l15][kc * 32 + q * 8]);
            #pragma unroll
            for (int nt = 0; nt < 4; ++nt) {
                bf16x8 bfr = *((const bf16x8*)&Bs[nt * 16 + l15][kc * 32 + q * 8]);
                acc[nt] = __builtin_amdgcn_mfma_f32_16x16x32_bf16(af, bfr, acc[nt], 0, 0, 0);
            }
        }
        __syncthreads();
    }

    #pragma unroll
    for (int nt = 0; nt < 4; ++nt) {
        int n = n0 + nt * 16 + l15;
        float bsum = bias1[n] + (bias2 ? bias2[n] : 0.f);
        #pragma unroll
        for (int rg = 0; rg < 4; ++rg) {
            int m = m0 + w * 16 + q * 4 + rg;     // D: row m = quad*4+reg, col n = lane&15
            float val = acc[nt][rg] + bsum;
            if (out_mode == 0) {
                C[(size_t)m * N + n] = val;
            } else {
                int t = m & (T_ - 1), b = m >> 10;
                C[((size_t)((t << 4) + b) << 10) + n] = val;
            }
        }
    }
}

// ---------------- LSTM scan: 1 WG/batch, 1024 threads, quad-per-hidden-unit ---------
// lane 4k+j computes gate-row j*256+k (j: 0=i 1=f 2=g 3=o, k = hidden unit).
// Per-thread weights: 64 int8x4 dwords = 64 VGPRs (fits 4 waves/SIMD @ <=128 VGPR,
// no AGPR demotion). Gate exchange is quad-local via __shfl_xor 1/2/3.
// h quantized with FIXED scale 127 (|h|<1). One raw s_barrier per step; no vmcnt
// drain, so the xproj prefetch and hs store stay in flight across the barrier.
__global__ __launch_bounds__(1024, 4)
void lstm_scan_kernel(const int* __restrict__ wq,
                      const float* __restrict__ wscale,
                      const float* __restrict__ xproj,
                      __hip_bfloat16* __restrict__ hs) {
    __shared__ __align__(16) int h_lds[2][64];  // 256 int8 h values, double buffered

    const int tid = threadIdx.x;   // 1024
    const int b = blockIdx.x;      // 16
    const int j = tid & 3;         // gate: 0=i 1=f 2=g 3=o
    const int k = tid >> 2;        // hidden unit 0..255
    const int r = j * 256 + k;     // gate-matrix row

    // load weight row (256 int8 = 64 VGPRs)
    int w[64];
    {
        const int4* p = (const int4*)wq + r * 16;
        #pragma unroll
        for (int i = 0; i < 16; ++i) {
            int4 a = p[i];
            w[4 * i + 0] = a.x; w[4 * i + 1] = a.y; w[4 * i + 2] = a.z; w[4 * i + 3] = a.w;
        }
    }
    const float qs = wscale[r] * (1.f / 127.f);  // weight scale * fixed h scale
    // act: j==2 -> tanh(x)=2*sigmoid(2x)-1 ; else sigmoid(x). Branchless per-lane consts.
    const float kb = (j == 2) ? 2.f : 1.f;
    const float nb = (j == 2) ? -1.f : 0.f;
    const bool j1 = (j & 1) != 0;
    const bool j2v = (j & 2) != 0;

    if (tid < 64) h_lds[0][tid] = 0;
    float c = 0.f;
    float xp = xproj[(b << 10) + r];
    __syncthreads();

    for (int t = 0; t < T_; ++t) {
        // prefetch next timestep's xproj (consumed after the barrier, ~1 step of cover)
        float nx = 0.f;
        if (t < T_ - 1) nx = xproj[(((size_t)(((t + 1) << 4) + b)) << 10) + r];

        int acc0 = 0, acc1 = 0;
        const int* hb = h_lds[t & 1];
        #pragma unroll
        for (int kd = 0; kd < 8; ++kd) {
            int4 hv = *((const int4*)(hb + kd * 4));   // broadcast read
            acc0 = SDOT4(w[4 * kd + 0], hv.x, acc0);
            acc1 = SDOT4(w[4 * kd + 1], hv.y, acc1);
            acc0 = SDOT4(w[4 * kd + 2], hv.z, acc0);
            acc1 = SDOT4(w[4 * kd + 3], hv.w, acc1);
        }
        #pragma unroll
        for (int kd = 8; kd < 16; ++kd) {
            int4 hv = *((const int4*)(hb + kd * 4));
            acc0 = SDOT4(w[4 * kd + 0], hv.x, acc0);
            acc1 = SDOT4(w[4 * kd + 1], hv.y, acc1);
            acc0 = SDOT4(w[4 * kd + 2], hv.z, acc0);
            acc1 = SDOT4(w[4 * kd + 3], hv.w, acc1);
        }
        float ga = (float)(acc0 + acc1) * qs + xp;   // pre-activation for my gate row
        float a  = sigmoid_f(kb * ga) * kb + nb;     // i/f/o: sigma ; g: tanh

        // quad exchange: gather all 4 gate values of hidden unit k
        float e1 = __shfl_xor(a, 1, 64);             // partner j^1
        float e2 = __shfl_xor(a, 2, 64);             // partner j^2
        float e3 = __shfl_xor(a, 3, 64);             // partner j^3
        // lane j holds a=act(j), e1=act(j^1), e2=act(j^2), e3=act(j^3)
        float s1a = j1 ? e1 : a;    // act(0) within low pair-view
        float s1b = j1 ? a  : e1;   // act(1)
        float s1c = j1 ? e3 : e2;   // act(2) 
        float s1d = j1 ? e2 : e3;   // act(3)
        float iv = j2v ? s1c : s1a;
        float fv = j2v ? s1d : s1b;
        float gv = j2v ? s1a : s1c;
        float ov = j2v ? s1b : s1d;
        // wait: mapping check. For j=0: a=i,e1=f,e2=g,e3=o -> s1a=i,s1b=f,s1c=g,s1d=o
        //   iv=s1a=i fv=s1b=f gv=s1c=g ov=s1d=o  (j2v=0)  OK
        // j=1: a=f,e1=i,e2=o,e3=g -> s1a=i,s1b=f,s1c=g,s1d=o OK
        // j=2: a=g,e1=o,e2=i,e3=f -> s1a=g,s1b=o,s1c=i,s1d=f ; j2v=1 -> iv=s1c=i fv=s1d=f gv=s1a=g ov=s1b=o OK
        // j=3: a=o,e1=g,e2=f,e3=i -> s1a=g,s1b=o,s1c=i,s1d=f ; iv=i fv=f gv=g ov=o OK
        c = fv * c + iv * gv;                        // replicated across the quad
        float th = 2.f * sigmoid_f(c + c) - 1.f;     // tanh(c)
        float h = ov * th;
        if (j == 0) {
            hs[(((size_t)(b << 10) + t) << 8) + k] = __float2bfloat16(h);
            ((signed char*)h_lds[(t + 1) & 1])[k] =
                (signed char)__float2int_rn(h * 127.f);   // |h|<1 -> no clamp needed
        }
        // LDS-only barrier: drain ds ops, rendezvous, fence the scheduler.
        // Deliberately NO vmcnt drain (prefetch + hs store stay in flight).
        asm volatile("s_waitcnt lgkmcnt(0)" ::: "memory");
        __builtin_amdgcn_s_barrier();
        __builtin_amdgcn_sched_barrier(0);
        xp = nx;
    }
}

extern "C" void kernel_launch(void* const* d_in, const int* in_sizes, int n_in,
                              void* d_out, int out_size, void* d_ws, size_t ws_size,
                              hipStream_t stream) {
    const int* x            = (const int*)d_in[0];
    const float* embed_x_w  = (const float*)d_in[1];
    const float* embed_lb_w = (const float*)d_in[2];
    const float* W_ih       = (const float*)d_in[3];
    const float* W_hh       = (const float*)d_in[4];
    const float* b_ih       = (const float*)d_in[5];
    const float* b_hh       = (const float*)d_in[6];
    const float* fc_w       = (const float*)d_in[7];
    const float* fc_b       = (const float*)d_in[8];
    float* out = (float*)d_out;

    char* ws = (char*)d_ws;
    __hip_bfloat16* inp_bf = (__hip_bfloat16*)(ws);                 //  8,388,608 B
    __hip_bfloat16* wih_bf = (__hip_bfloat16*)(ws + 8388608);       //    524,288 B
    __hip_bfloat16* fcw_bf = (__hip_bfloat16*)(ws + 8912896);       //  4,096,000 B
    int*   whh_q           = (int*)(ws + 13008896);                 //    262,144 B
    float* whh_s           = (float*)(ws + 13271040);               //      4,096 B
    float* xproj           = (float*)(ws + 13275136);               // 67,108,864 B
    __hip_bfloat16* hs     = (__hip_bfloat16*)(ws + 80384000);      //  8,388,608 B
    (void)in_sizes; (void)n_in; (void)out_size; (void)ws_size;

    hipLaunchKernelGGL(embed_kernel, dim3(M_), dim3(256), 0, stream,
                       x, embed_x_w, embed_lb_w, inp_bf);
    hipLaunchKernelGGL(f2bf_kernel, dim3((G4_ * HID_ + 255) / 256), dim3(256), 0, stream,
                       W_ih, wih_bf, G4_ * HID_);
    hipLaunchKernelGGL(f2bf_kernel, dim3((NC_ * HID_ + 255) / 256), dim3(256), 0, stream,
                       fc_w, fcw_bf, NC_ * HID_);
    hipLaunchKernelGGL(quant_whh_kernel, dim3(G4_), dim3(64), 0, stream,
                       W_hh, whh_q, whh_s);
    // x_proj: (t,b,1024) = inp @ W_ih^T + b_ih + b_hh
    hipLaunchKernelGGL(gemm_bf16_kernel, dim3(G4_ / 64, M_ / 64), dim3(256), 0, stream,
                       inp_bf, wih_bf, b_ih, b_hh, xproj, G4_, 1);
    // sequential LSTM over T, one WG per batch element
    hipLaunchKernelGGL(lstm_scan_kernel, dim3(B_), dim3(1024), 0, stream,
                       whh_q, whh_s, xproj, hs);
    // out: (b,t,8000) = hs @ fc_w^T + fc_b
    hipLaunchKernelGGL(gemm_bf16_kernel, dim3(NC_ / 64, M_ / 64), dim3(256), 0, stream,
                       hs, fcw_bf, fc_b, (const float*)nullptr, out, NC_, 0);
}

// Round 3
// 1431.209 us; speedup vs baseline: 1.1964x; 1.1964x over previous
//
#include <hip/hip_runtime.h>
#include <hip/hip_bf16.h>
#include <stdint.h>

#define B_ 16
#define T_ 1024
#define EMBED_ 128
#define HID_ 256
#define G4_ 1024
#define NC_ 8000
#define M_ (B_*T_)

typedef short bf16x8 __attribute__((ext_vector_type(8)));
typedef float f32x4 __attribute__((ext_vector_type(4)));
typedef unsigned int u32;

#if defined(__has_builtin)
#if __has_builtin(__builtin_amdgcn_sdot4)
#define SDOT4(a,b,c) __builtin_amdgcn_sdot4((a),(b),(c),false)
#endif
#endif
#ifndef SDOT4
__device__ __forceinline__ int sdot4_sw(int a, int b, int c) {
    c += (int)(signed char)(a)       * (int)(signed char)(b);
    c += (int)(signed char)(a >> 8)  * (int)(signed char)(b >> 8);
    c += (int)(signed char)(a >> 16) * (int)(signed char)(b >> 16);
    c += (int)(signed char)(a >> 24) * (int)(signed char)(b >> 24);
    return c;
}
#define SDOT4(a,b,c) sdot4_sw((a),(b),(c))
#endif

__device__ __forceinline__ float sigmoid_f(float x) {
    float e = __expf(-x);
    return __builtin_amdgcn_rcpf(1.f + e);   // x<<0: e=inf -> 0 ; x>>0: e=0 -> 1
}

// pair exchange lanes (2k)<->(2k+1) at VALU speed: quad_perm [1,0,3,2] = 0xB1
__device__ __forceinline__ float dpp_swap1(float x) {
    int i = __builtin_amdgcn_mov_dpp(__float_as_int(x), 0xB1, 0xF, 0xF, true);
    return __int_as_float(i);
}

// async global->LDS, 16B per lane; lds dest must be wave-uniform base (HW adds lane*16)
#define GLD_LDS16(gsrc, ldst) \
    __builtin_amdgcn_global_load_lds((const __attribute__((address_space(1))) u32*)(gsrc), \
                                     (__attribute__((address_space(3))) u32*)(ldst), 16, 0, 0)

// ---------------- embed + concat -> bf16 (16384 x 256) ----------------
__global__ void embed_kernel(const int* __restrict__ x,
                             const float* __restrict__ ew,
                             const float* __restrict__ lw,
                             __hip_bfloat16* __restrict__ inp) {
    int m = blockIdx.x;          // b*T + t
    int e = threadIdx.x;         // 0..255
    int i0 = x[2 * m];
    int i1 = x[2 * m + 1];
    float v = (e < EMBED_) ? ew[i0 * EMBED_ + e] : lw[i1 * EMBED_ + (e - EMBED_)];
    inp[m * 256 + e] = __float2bfloat16(v);
}

// ---------------- f32 -> bf16 ----------------
__global__ void f2bf_kernel(const float* __restrict__ in,
                            __hip_bfloat16* __restrict__ out, int n) {
    int i = blockIdx.x * blockDim.x + threadIdx.x;
    if (i < n) out[i] = __float2bfloat16(in[i]);
}

// ---------------- per-row int8 quant of W_hh (1024 rows x 256) ----------------
__global__ void quant_whh_kernel(const float* __restrict__ whh,
                                 int* __restrict__ wq, float* __restrict__ wscale) {
    int r = blockIdx.x;      // 1024
    int lane = threadIdx.x;  // 64
    float4 v = ((const float4*)(whh + r * HID_))[lane];
    float m = fmaxf(fmaxf(fabsf(v.x), fabsf(v.y)), fmaxf(fabsf(v.z), fabsf(v.w)));
    #pragma unroll
    for (int off = 32; off; off >>= 1) m = fmaxf(m, __shfl_xor(m, off, 64));
    m = fmaxf(m, 1e-20f);
    float inv = 127.f / m;
    int q0 = __float2int_rn(v.x * inv) & 255;
    int q1 = __float2int_rn(v.y * inv) & 255;
    int q2 = __float2int_rn(v.z * inv) & 255;
    int q3 = __float2int_rn(v.w * inv) & 255;
    wq[r * 64 + lane] = q0 | (q1 << 8) | (q2 << 16) | (q3 << 24);
    if (lane == 0) wscale[r] = m * (1.f / 127.f);
}

// ---------------- bf16 MFMA GEMM (64x64 tile, used for xproj) ----------------
__global__ __launch_bounds__(256, 4)
void gemm_bf16_kernel(const __hip_bfloat16* __restrict__ A,
                      const __hip_bfloat16* __restrict__ Bm,
                      const float* __restrict__ bias1,
                      const float* __restrict__ bias2,
                      float* __restrict__ C,
                      int N, int out_mode) {
    __shared__ short As[64][136];   // pad: row stride 272B -> 2-way bank alias (free)
    __shared__ short Bs[64][136];
    const int tid = threadIdx.x;
    const int m0 = blockIdx.y * 64;
    const int n0 = blockIdx.x * 64;
    const int w = tid >> 6;
    const int lane = tid & 63;
    const int l15 = lane & 15;
    const int q = lane >> 4;

    f32x4 zero4 = {0.f, 0.f, 0.f, 0.f};
    f32x4 acc[4] = {zero4, zero4, zero4, zero4};

    const int r = tid >> 2;
    const int cbase = tid & 3;

    for (int ko = 0; ko < 256; ko += 128) {
        #pragma unroll
        for (int i = 0; i < 4; ++i) {
            int c = cbase + (i << 2);  // 0..15 chunks of 8 elems
            uint4 av = ((const uint4*)A)[(size_t)(m0 + r) * 32 + (ko >> 3) + c];
            *((uint4*)&As[r][c * 8]) = av;
            uint4 bv = ((const uint4*)Bm)[(size_t)(n0 + r) * 32 + (ko >> 3) + c];
            *((uint4*)&Bs[r][c * 8]) = bv;
        }
        __syncthreads();
        #pragma unroll
        for (int kc = 0; kc < 4; ++kc) {
            bf16x8 af = *((const bf16x8*)&As[w * 16 + l15][kc * 32 + q * 8]);
            #pragma unroll
            for (int nt = 0; nt < 4; ++nt) {
                bf16x8 bfr = *((const bf16x8*)&Bs[nt * 16 + l15][kc * 32 + q * 8]);
                acc[nt] = __builtin_amdgcn_mfma_f32_16x16x32_bf16(af, bfr, acc[nt], 0, 0, 0);
            }
        }
        __syncthreads();
    }

    #pragma unroll
    for (int nt = 0; nt < 4; ++nt) {
        int n = n0 + nt * 16 + l15;
        float bsum = bias1[n] + (bias2 ? bias2[n] : 0.f);
        #pragma unroll
        for (int rg = 0; rg < 4; ++rg) {
            int m = m0 + w * 16 + q * 4 + rg;     // D: row m = quad*4+reg, col n = lane&15
            float val = acc[nt][rg] + bsum;
            if (out_mode == 0) {
                C[(size_t)m * N + n] = val;
            } else {
                int t = m & (T_ - 1), b = m >> 10;
                C[((size_t)((t << 4) + b) << 10) + n] = val;
            }
        }
    }
}

// ---------------- fc GEMM: 128x64 tile, BK=64, global_load_lds + XOR swizzle -------
// C[m, n] = sum_k A[m,k]*B[n,k] + bias[n];  A: M x 256, B: 8000 x 256, C: M x 8000.
// LDS rows are 64 bf16 = 128 B -> unswizzled ds_read would be 16-way bank conflict.
// T2 swizzle st-style: byte ^= (row&7)<<4, applied on the GLOBAL source address
// (gload_lds dest must stay linear) and on the ds_read address (rule #21).
__global__ __launch_bounds__(256, 4)
void gemm_fc_kernel(const __hip_bfloat16* __restrict__ A,
                    const __hip_bfloat16* __restrict__ Bm,
                    const float* __restrict__ bias,
                    float* __restrict__ C) {
    __shared__ __align__(16) short As[128 * 64];   // 16 KB
    __shared__ __align__(16) short Bs[64 * 64];    //  8 KB
    const int tid  = threadIdx.x;
    const int wid  = tid >> 6;
    const int lane = tid & 63;
    const int m0 = blockIdx.y * 128;
    const int n0 = blockIdx.x * 64;
    const int l15 = lane & 15;
    const int q = lane >> 4;

    f32x4 zero4 = {0.f, 0.f, 0.f, 0.f};
    f32x4 acc[2][4];
    #pragma unroll
    for (int mf = 0; mf < 2; ++mf)
        #pragma unroll
        for (int nf = 0; nf < 4; ++nf) acc[mf][nf] = zero4;

    const int srow = (wid << 3) + (lane >> 3);     // 0..31 within a 32-row issue
    const int scl  = (lane & 7) << 4;              // linear col-byte 0..112

    for (int ko = 0; ko < 256; ko += 64) {
        // stage A: 4 issues x 32 rows (each wave: 8 rows x 128 B = 1 KB linear)
        #pragma unroll
        for (int is = 0; is < 4; ++is) {
            int row = (is << 5) + srow;
            int cb  = scl ^ ((row & 7) << 4);       // inverse-swizzled source col
            const char* gp = (const char*)(A + (size_t)(m0 + row) * 256) + ko * 2 + cb;
            char* lp = (char*)As + (is << 12) + (wid << 10);  // wave-uniform base
            GLD_LDS16(gp, lp);
        }
        // stage B: 2 issues x 32 rows
        #pragma unroll
        for (int is = 0; is < 2; ++is) {
            int row = (is << 5) + srow;
            int cb  = scl ^ ((row & 7) << 4);
            const char* gp = (const char*)(Bm + (size_t)(n0 + row) * 256) + ko * 2 + cb;
            char* lp = (char*)Bs + (is << 12) + (wid << 10);
            GLD_LDS16(gp, lp);
        }
        __syncthreads();
        #pragma unroll
        for (int kc = 0; kc < 2; ++kc) {
            const int kb = kc * 64 + q * 16;        // byte offset within 128 B row
            #pragma unroll
            for (int mf = 0; mf < 2; ++mf) {
                const int ar = (wid << 5) + mf * 16 + l15;
                bf16x8 af = *(const bf16x8*)((const char*)As + ar * 128 + (kb ^ ((ar & 7) << 4)));
                #pragma unroll
                for (int nf = 0; nf < 4; ++nf) {
                    const int br = nf * 16 + l15;
                    bf16x8 bf = *(const bf16x8*)((const char*)Bs + br * 128 + (kb ^ ((br & 7) << 4)));
                    acc[mf][nf] = __builtin_amdgcn_mfma_f32_16x16x32_bf16(af, bf, acc[mf][nf], 0, 0, 0);
                }
            }
        }
        __syncthreads();
    }

    #pragma unroll
    for (int nf = 0; nf < 4; ++nf) {
        int n = n0 + nf * 16 + l15;
        float bs = bias[n];
        #pragma unroll
        for (int mf = 0; mf < 2; ++mf) {
            #pragma unroll
            for (int rg = 0; rg < 4; ++rg) {
                int m = m0 + (wid << 5) + mf * 16 + q * 4 + rg;
                C[(size_t)m * NC_ + n] = acc[mf][nf][rg] + bs;
            }
        }
    }
}

// ---------------- LSTM scan: 1 WG per batch, lane-paired gates (round-1 base) -------
// thread 2k: rows k (i), 512+k (g); thread 2k+1: rows 256+k (f), 768+k (o).
// Changes vs round 1: DPP quad_perm pair exchange (VALU-speed, no ds_bpermute),
// bursted h reads (hv[16] before dot chain), 4 accumulators, h ds_write before the
// global hs store, no sched_barrier (asm "memory" clobber orders the LDS ops).
__global__ __launch_bounds__(512, 2)
void lstm_scan_kernel(const int* __restrict__ wq,
                      const float* __restrict__ wscale,
                      const float* __restrict__ xproj,
                      __hip_bfloat16* __restrict__ hs) {
    __shared__ __align__(16) int h_lds[2][64];  // 256 int8 h values, double buffered

    const int tid = threadIdx.x;   // 512
    const int b = blockIdx.x;      // 16
    const int u = tid >> 1;        // hidden unit 0..255
    const int odd = tid & 1;
    const int r0 = odd ? (256 + u) : u;           // f : i
    const int r1 = odd ? (768 + u) : (512 + u);   // o : g

    int w0[64], w1[64];
    {
        const int4* p0 = (const int4*)wq + r0 * 16;
        const int4* p1 = (const int4*)wq + r1 * 16;
        #pragma unroll
        for (int i = 0; i < 16; ++i) {
            int4 a = p0[i];
            w0[4 * i + 0] = a.x; w0[4 * i + 1] = a.y; w0[4 * i + 2] = a.z; w0[4 * i + 3] = a.w;
            int4 bb = p1[i];
            w1[4 * i + 0] = bb.x; w1[4 * i + 1] = bb.y; w1[4 * i + 2] = bb.z; w1[4 * i + 3] = bb.w;
        }
    }
    const float qs0 = wscale[r0] * (1.f / 127.f);
    const float qs1 = wscale[r1] * (1.f / 127.f);
    const float kb = odd ? 1.f : 2.f;   // even: tanh(x)=2*sigma(2x)-1
    const float mb = odd ? 1.f : 2.f;
    const float nb = odd ? 0.f : -1.f;

    if (tid < 64) h_lds[0][tid] = 0;
    float c = 0.f;
    float xp0 = xproj[(b << 10) + r0];
    float xp1 = xproj[(b << 10) + r1];
    __syncthreads();

    for (int t = 0; t < T_; ++t) {
        float nx0 = 0.f, nx1 = 0.f;
        if (t < T_ - 1) {
            const float* p = xproj + ((size_t)(((t + 1) << 4) + b) << 10);
            nx0 = p[r0];
            nx1 = p[r1];
        }
        // burst-read all of h (16 x b128 broadcast) before the dot chains
        const int4* hb = (const int4*)h_lds[t & 1];
        int4 hv[16];
        #pragma unroll
        for (int i = 0; i < 16; ++i) hv[i] = hb[i];

        int a00 = 0, a01 = 0, a10 = 0, a11 = 0;   // 2 rows x 2 chains
        #pragma unroll
        for (int kd = 0; kd < 8; ++kd) {
            a00 = SDOT4(w0[4 * kd + 0], hv[kd].x, a00);
            a01 = SDOT4(w0[4 * kd + 1], hv[kd].y, a01);
            a00 = SDOT4(w0[4 * kd + 2], hv[kd].z, a00);
            a01 = SDOT4(w0[4 * kd + 3], hv[kd].w, a01);
            a10 = SDOT4(w1[4 * kd + 0], hv[kd].x, a10);
            a11 = SDOT4(w1[4 * kd + 1], hv[kd].y, a11);
            a10 = SDOT4(w1[4 * kd + 2], hv[kd].z, a10);
            a11 = SDOT4(w1[4 * kd + 3], hv[kd].w, a11);
        }
        #pragma unroll
        for (int kd = 8; kd < 16; ++kd) {
            a00 = SDOT4(w0[4 * kd + 0], hv[kd].x, a00);
            a01 = SDOT4(w0[4 * kd + 1], hv[kd].y, a01);
            a00 = SDOT4(w0[4 * kd + 2], hv[kd].z, a00);
            a01 = SDOT4(w0[4 * kd + 3], hv[kd].w, a01);
            a10 = SDOT4(w1[4 * kd + 0], hv[kd].x, a10);
            a11 = SDOT4(w1[4 * kd + 1], hv[kd].y, a11);
            a10 = SDOT4(w1[4 * kd + 2], hv[kd].z, a10);
            a11 = SDOT4(w1[4 * kd + 3], hv[kd].w, a11);
        }
        float ga = (float)(a00 + a01) * qs0 + xp0;   // i (even) / f (odd)
        float gb = (float)(a10 + a11) * qs1 + xp1;   // g (even) / o (odd)
        float a0 = sigmoid_f(ga);
        float a1 = sigmoid_f(kb * gb) * mb + nb;
        float pa0 = dpp_swap1(a0);                   // partner's f / i
        float pa1 = dpp_swap1(a1);                   // partner's o / g
        float iv = odd ? pa0 : a0;
        float fv = odd ? a0 : pa0;
        float gv = odd ? pa1 : a1;
        float ov = odd ? a1 : pa1;
        c = fv * c + iv * gv;                        // replicated on both lanes
        float th = 2.f * sigmoid_f(c + c) - 1.f;     // tanh(c)
        float h = ov * th;
        if (!odd) {
            // critical path first: publish quantized h for t+1
            ((signed char*)h_lds[(t + 1) & 1])[u] =
                (signed char)__float2int_rn(h * 127.f);   // |h|<1 -> no clamp needed
            // off-path: hs global store (vmcnt never drained in-loop)
            hs[(((size_t)(b << 10) + t) << 8) + u] = __float2bfloat16(h);
        }
        // LDS-only barrier: drain ds ops, rendezvous. NO vmcnt drain; the "memory"
        // clobber orders LDS ops at compiler level (no sched_barrier needed).
        asm volatile("s_waitcnt lgkmcnt(0)" ::: "memory");
        __builtin_amdgcn_s_barrier();
        xp0 = nx0;
        xp1 = nx1;
    }
}

extern "C" void kernel_launch(void* const* d_in, const int* in_sizes, int n_in,
                              void* d_out, int out_size, void* d_ws, size_t ws_size,
                              hipStream_t stream) {
    const int* x            = (const int*)d_in[0];
    const float* embed_x_w  = (const float*)d_in[1];
    const float* embed_lb_w = (const float*)d_in[2];
    const float* W_ih       = (const float*)d_in[3];
    const float* W_hh       = (const float*)d_in[4];
    const float* b_ih       = (const float*)d_in[5];
    const float* b_hh       = (const float*)d_in[6];
    const float* fc_w       = (const float*)d_in[7];
    const float* fc_b       = (const float*)d_in[8];
    float* out = (float*)d_out;

    char* ws = (char*)d_ws;
    __hip_bfloat16* inp_bf = (__hip_bfloat16*)(ws);                 //  8,388,608 B
    __hip_bfloat16* wih_bf = (__hip_bfloat16*)(ws + 8388608);       //    524,288 B
    __hip_bfloat16* fcw_bf = (__hip_bfloat16*)(ws + 8912896);       //  4,096,000 B
    int*   whh_q           = (int*)(ws + 13008896);                 //    262,144 B
    float* whh_s           = (float*)(ws + 13271040);               //      4,096 B
    float* xproj           = (float*)(ws + 13275136);               // 67,108,864 B
    __hip_bfloat16* hs     = (__hip_bfloat16*)(ws + 80384000);      //  8,388,608 B
    (void)in_sizes; (void)n_in; (void)out_size; (void)ws_size;

    hipLaunchKernelGGL(embed_kernel, dim3(M_), dim3(256), 0, stream,
                       x, embed_x_w, embed_lb_w, inp_bf);
    hipLaunchKernelGGL(f2bf_kernel, dim3((G4_ * HID_ + 255) / 256), dim3(256), 0, stream,
                       W_ih, wih_bf, G4_ * HID_);
    hipLaunchKernelGGL(f2bf_kernel, dim3((NC_ * HID_ + 255) / 256), dim3(256), 0, stream,
                       fc_w, fcw_bf, NC_ * HID_);
    hipLaunchKernelGGL(quant_whh_kernel, dim3(G4_), dim3(64), 0, stream,
                       W_hh, whh_q, whh_s);
    // x_proj: (t,b,1024) = inp @ W_ih^T + b_ih + b_hh
    hipLaunchKernelGGL(gemm_bf16_kernel, dim3(G4_ / 64, M_ / 64), dim3(256), 0, stream,
                       inp_bf, wih_bf, b_ih, b_hh, xproj, G4_, 1);
    // sequential LSTM over T, one WG per batch element
    hipLaunchKernelGGL(lstm_scan_kernel, dim3(B_), dim3(512), 0, stream,
                       whh_q, whh_s, xproj, hs);
    // out: (b,t,8000) = hs @ fc_w^T + fc_b  (128x64 tile, gload_lds + swizzle)
    hipLaunchKernelGGL(gemm_fc_kernel, dim3(NC_ / 64, M_ / 128), dim3(256), 0, stream,
                       hs, fcw_bf, fc_b, out);
}